// Round 5
// baseline (226.352 us; speedup 1.0000x reference)
//
#include <hip/hip_runtime.h>
#include <hip/hip_bf16.h>
#include <math.h>

// TriangleAttention B=1,N=256,D=128,H=4,DH=32. Round 5: ln_proj v3 (all-register LN,
// no scalar-load latency chains). attn/gateout unchanged from the passing round-4 build.
//  K0 prep:    weights fp32 -> bf16 (WB = [wqkv;wgate] 512x128, WO 128x128)
//  K1 ln_proj: per-thread 32-elem row slice in regs -> LN stats via 2 shuffles ->
//              in-register pair-bias (4 heads, shuffle-reduced) -> bf16 pack -> LDS A
//              (XOR-swizzled, 16KB) -> MFMA GEMM 64x512x128 -> Q/K/V head-major bf16,
//              gate bf16 (sigmoid), pair-bias f32
//  K2 attn:    per (i,h): QK^T MFMA -> +bias, exp (no max-sub: |S| small) -> P bf16
//              via LDS -> PV MFMA -> /sum -> ao bf16
//  K3 gateout: x = gate*ao (bf16) -> MFMA GEMM 64x128x128 -> out f32

#define NDIM 256
#define DDIM 128
#define NROWS 65536
#define ATT_SCALE 0.17677669529663687f
#define LN_EPS 1e-5f

typedef __attribute__((ext_vector_type(8))) short short8;
typedef __attribute__((ext_vector_type(4))) float f32x4;

#define MFMA16(a, b, c) __builtin_amdgcn_mfma_f32_16x16x32_bf16((a), (b), (c), 0, 0, 0)

__device__ inline unsigned short f2b(float x) {
    __hip_bfloat16 h = __float2bfloat16(x);
    return *reinterpret_cast<unsigned short*>(&h);
}
__device__ inline float b2f(unsigned short u) {
    return __uint_as_float(((unsigned int)u) << 16);
}

// ---------------- K0: weight prep ----------------
__global__ __launch_bounds__(256) void prep_kernel(
    const float* __restrict__ wqkv, const float* __restrict__ wgate,
    const float* __restrict__ wout,
    unsigned short* __restrict__ WB, unsigned short* __restrict__ WO)
{
    int idx = blockIdx.x * 256 + threadIdx.x;
    if (idx < 49152)      WB[idx] = f2b(wqkv[idx]);
    else if (idx < 65536) WB[idx] = f2b(wgate[idx - 49152]);
    else if (idx < 81920) WO[idx - 65536] = f2b(wout[idx - 65536]);
}

// ---------------- K1: LN + projections (v3: register LN) ----------------
__global__ __launch_bounds__(256) void ln_proj_kernel(
    const float* __restrict__ z, const float* __restrict__ nw, const float* __restrict__ nb,
    const float* __restrict__ wbias, const unsigned short* __restrict__ WB,
    unsigned short* __restrict__ Qb, unsigned short* __restrict__ Kb,
    unsigned short* __restrict__ Vb, unsigned short* __restrict__ Gb,
    float* __restrict__ bias)
{
    __shared__ __align__(16) unsigned short A[64 * 128];   // 16 KB only
    const int tid = threadIdx.x;
    const int r0 = blockIdx.x * 64;
    const int r = tid >> 2;          // row within tile (4 consecutive lanes per row)
    const int part = tid & 3;        // 32-elem slice of the row
    const int d0 = part * 32;

    // --- load z slice: 8 independent float4 loads, registers only ---
    float4 zv[8];
    const float* zrow = z + (size_t)(r0 + r) * DDIM + d0;
    #pragma unroll
    for (int t = 0; t < 8; ++t) zv[t] = *reinterpret_cast<const float4*>(zrow + t * 4);

    // --- LN stats via 2 shuffles in the 4-lane row group ---
    float s1 = 0.f, s2 = 0.f;
    #pragma unroll
    for (int t = 0; t < 8; ++t) {
        s1 += zv[t].x + zv[t].y + zv[t].z + zv[t].w;
        s2 += zv[t].x * zv[t].x + zv[t].y * zv[t].y + zv[t].z * zv[t].z + zv[t].w * zv[t].w;
    }
    s1 += __shfl_xor(s1, 1); s2 += __shfl_xor(s2, 1);
    s1 += __shfl_xor(s1, 2); s2 += __shfl_xor(s2, 2);
    const float mu = s1 * (1.0f / 128.0f);
    const float rs = rsqrtf(s2 * (1.0f / 128.0f) - mu * mu + LN_EPS);

    // --- normalize in registers (batched float4 weight loads, L2-resident) ---
    float zn[32];
    {
        #pragma unroll
        for (int t = 0; t < 8; ++t) {
            float4 wv = *reinterpret_cast<const float4*>(nw + d0 + t * 4);
            float4 bv = *reinterpret_cast<const float4*>(nb + d0 + t * 4);
            zn[t * 4 + 0] = (zv[t].x - mu) * rs * wv.x + bv.x;
            zn[t * 4 + 1] = (zv[t].y - mu) * rs * wv.y + bv.y;
            zn[t * 4 + 2] = (zv[t].z - mu) * rs * wv.z + bv.z;
            zn[t * 4 + 3] = (zv[t].w - mu) * rs * wv.w + bv.w;
        }
    }

    // --- pair bias: 4 head-partials over this slice, shuffle-reduce over 4 lanes ---
    {
        float p[4];
        #pragma unroll
        for (int h = 0; h < 4; ++h) {
            const float* wb = wbias + h * DDIM + d0;
            float acc = 0.f;
            #pragma unroll
            for (int t = 0; t < 8; ++t) {
                float4 wv = *reinterpret_cast<const float4*>(wb + t * 4);
                acc += zn[t * 4 + 0] * wv.x + zn[t * 4 + 1] * wv.y
                     + zn[t * 4 + 2] * wv.z + zn[t * 4 + 3] * wv.w;
            }
            p[h] = acc;
        }
        #pragma unroll
        for (int h = 0; h < 4; ++h) {
            p[h] += __shfl_xor(p[h], 1);
            p[h] += __shfl_xor(p[h], 2);
        }
        // lane `part` owns head `part` (static select, no dynamic reg indexing)
        float sel = (part == 0) ? p[0] : (part == 1) ? p[1] : (part == 2) ? p[2] : p[3];
        bias[(size_t)part * NROWS + r0 + r] = sel;
    }

    // --- pack to bf16, write swizzled A (4 vector stores) ---
    #pragma unroll
    for (int e = 0; e < 4; ++e) {
        short8 t;
        #pragma unroll
        for (int q = 0; q < 8; ++q) t[q] = (short)f2b(zn[e * 8 + q]);
        int dd = d0 + e * 8;
        *reinterpret_cast<short8*>(&A[r * 128 + (dd ^ ((r & 7) << 3))]) = t;
    }
    __syncthreads();

    // --- MFMA GEMM: 64 rows x 512 cols, K=128. wave tile 64x64, 2 col-chunks ---
    const int w = tid >> 6, lane = tid & 63, lr = lane & 15, lg = lane >> 4;
    for (int chunk = 0; chunk < 2; ++chunk) {
        const int cb = chunk * 256 + w * 64;
        f32x4 acc[4][4] = {};
        #pragma unroll
        for (int kk = 0; kk < 4; ++kk) {
            short8 af[4];
            #pragma unroll
            for (int m = 0; m < 4; ++m) {
                int rr_ = m * 16 + lr, dd = kk * 32 + lg * 8;
                af[m] = *reinterpret_cast<const short8*>(&A[rr_ * 128 + (dd ^ ((rr_ & 7) << 3))]);
            }
            #pragma unroll
            for (int n = 0; n < 4; ++n) {
                int c = cb + n * 16 + lr;
                short8 bf = *reinterpret_cast<const short8*>(WB + (size_t)c * 128 + kk * 32 + lg * 8);
                #pragma unroll
                for (int m = 0; m < 4; ++m)
                    acc[m][n] = MFMA16(af[m], bf, acc[m][n]);
            }
        }
        #pragma unroll
        for (int n = 0; n < 4; ++n) {
            int c = cb + n * 16 + lr;  // 16-aligned: q/k/v/gate + head uniform per n-tile
            #pragma unroll
            for (int m = 0; m < 4; ++m) {
                #pragma unroll
                for (int rr = 0; rr < 4; ++rr) {
                    int row = r0 + m * 16 + lg * 4 + rr;
                    float v = acc[m][n][rr];
                    if (c < 128) {
                        int h = c >> 5, d = c & 31;
                        Qb[((size_t)h * NROWS + row) * 32 + d] = f2b(v);
                    } else if (c < 256) {
                        int h = (c - 128) >> 5, d = c & 31;
                        Kb[((size_t)h * NROWS + row) * 32 + d] = f2b(v);
                    } else if (c < 384) {
                        int h = (c - 256) >> 5, d = c & 31;
                        Vb[((size_t)h * NROWS + row) * 32 + d] = f2b(v);
                    } else {
                        float s = 1.0f / (1.0f + __expf(-v));
                        Gb[(size_t)row * 128 + (c - 384)] = f2b(s);
                    }
                }
            }
        }
    }
}

// ---------------- K2: attention (unchanged from passing round-4 build) ----------------
__global__ __launch_bounds__(256) void attn_kernel(
    const unsigned short* __restrict__ Qb, const unsigned short* __restrict__ Kb,
    const unsigned short* __restrict__ Vb, const float* __restrict__ bias,
    unsigned short* __restrict__ ao)
{
    __shared__ __align__(16) unsigned short k_lds[256 * 40];   // pad 40: bank-safe
    __shared__ __align__(16) unsigned short vt_lds[32 * 264];  // V^T, pad 264
    __shared__ __align__(16) unsigned short p_lds[4][64 * 40];
    const int i = blockIdx.x >> 2, h = blockIdx.x & 3;
    const int tid = threadIdx.x;

    {   // stage K (row-major) and V^T
        int j = tid;
        const unsigned short* ks = Kb + ((size_t)h * NROWS + i * 256 + j) * 32;
        const unsigned short* vs = Vb + ((size_t)h * NROWS + i * 256 + j) * 32;
        #pragma unroll
        for (int c = 0; c < 4; ++c)
            *reinterpret_cast<short8*>(&k_lds[j * 40 + c * 8]) =
                *reinterpret_cast<const short8*>(ks + c * 8);
        unsigned short vv[32];
        #pragma unroll
        for (int c = 0; c < 4; ++c)
            *reinterpret_cast<short8*>(&vv[c * 8]) =
                *reinterpret_cast<const short8*>(vs + c * 8);
        #pragma unroll
        for (int d = 0; d < 32; ++d) vt_lds[d * 264 + j] = vv[d];
    }

    const int w = tid >> 6, lane = tid & 63, lr = lane & 15, lg = lane >> 4;
    short8 qf[4];
    #pragma unroll
    for (int m = 0; m < 4; ++m) {
        int jq = w * 64 + m * 16 + lr;
        qf[m] = *reinterpret_cast<const short8*>(
            Qb + ((size_t)h * NROWS + i * 256 + jq) * 32 + lg * 8);
    }
    f32x4 o[4][2] = {};
    float lsum[4][4] = {};
    const float* bb = bias + (size_t)h * NROWS;
    __syncthreads();

    for (int t = 0; t < 8; ++t) {
        const int k0 = t * 32;
        short8 kf[2];
        #pragma unroll
        for (int n = 0; n < 2; ++n)
            kf[n] = *reinterpret_cast<const short8*>(&k_lds[(k0 + n * 16 + lr) * 40 + lg * 8]);
        f32x4 s[4][2];
        #pragma unroll
        for (int m = 0; m < 4; ++m) {
            #pragma unroll
            for (int n = 0; n < 2; ++n) {
                f32x4 zz = {0.f, 0.f, 0.f, 0.f};
                s[m][n] = MFMA16(qf[m], kf[n], zz);
            }
        }
        // bias + exp (no max-subtraction: |S| bounded), write P bf16
        #pragma unroll
        for (int m = 0; m < 4; ++m) {
            #pragma unroll
            for (int rr = 0; rr < 4; ++rr) {
                int jq = w * 64 + m * 16 + lg * 4 + rr;
                #pragma unroll
                for (int n = 0; n < 2; ++n) {
                    int kc = k0 + n * 16 + lr;
                    float sv = s[m][n][rr] * ATT_SCALE + bb[(size_t)jq * 256 + kc];
                    float p = __expf(sv);
                    lsum[m][rr] += p;
                    p_lds[w][(m * 16 + lg * 4 + rr) * 40 + n * 16 + lr] = f2b(p);
                }
            }
        }
        // PV
        short8 vf[2], pf[4];
        #pragma unroll
        for (int n = 0; n < 2; ++n)
            vf[n] = *reinterpret_cast<const short8*>(&vt_lds[(n * 16 + lr) * 264 + k0 + lg * 8]);
        #pragma unroll
        for (int m = 0; m < 4; ++m)
            pf[m] = *reinterpret_cast<const short8*>(&p_lds[w][(m * 16 + lr) * 40 + lg * 8]);
        #pragma unroll
        for (int m = 0; m < 4; ++m) {
            #pragma unroll
            for (int n = 0; n < 2; ++n)
                o[m][n] = MFMA16(pf[m], vf[n], o[m][n]);
        }
    }

    #pragma unroll
    for (int m = 0; m < 4; ++m) {
        #pragma unroll
        for (int rr = 0; rr < 4; ++rr) {
            float l = lsum[m][rr];
            l += __shfl_xor(l, 1); l += __shfl_xor(l, 2);
            l += __shfl_xor(l, 4); l += __shfl_xor(l, 8);
            float inv = 1.0f / l;
            int jq = w * 64 + m * 16 + lg * 4 + rr;
            #pragma unroll
            for (int n = 0; n < 2; ++n) {
                float v = o[m][n][rr] * inv;
                ao[(size_t)(i * 256 + jq) * 128 + h * 32 + n * 16 + lr] = f2b(v);
            }
        }
    }
}

// ---------------- K3: gate * ao @ w_out (unchanged) ----------------
__global__ __launch_bounds__(256) void gateout_kernel(
    const unsigned short* __restrict__ Gb, const unsigned short* __restrict__ ao,
    const unsigned short* __restrict__ WO, float* __restrict__ out)
{
    __shared__ __align__(16) unsigned short A[64 * 128];
    const int tid = threadIdx.x;
    const int r0 = blockIdx.x * 64;

    for (int c = tid; c < 64 * 16; c += 256) {
        int r = c >> 4, d0 = (c & 15) * 8;
        size_t off = (size_t)(r0 + r) * 128 + d0;
        short8 gv = *reinterpret_cast<const short8*>(Gb + off);
        short8 av = *reinterpret_cast<const short8*>(ao + off);
        short8 t;
        #pragma unroll
        for (int e = 0; e < 8; ++e)
            t[e] = (short)f2b(b2f((unsigned short)gv[e]) * b2f((unsigned short)av[e]));
        *reinterpret_cast<short8*>(&A[r * 128 + (d0 ^ ((r & 7) << 3))]) = t;
    }
    __syncthreads();

    const int w = tid >> 6, lane = tid & 63, lr = lane & 15, lg = lane >> 4;
    f32x4 acc[4][2] = {};
    #pragma unroll
    for (int kk = 0; kk < 4; ++kk) {
        short8 af[4];
        #pragma unroll
        for (int m = 0; m < 4; ++m) {
            int r = m * 16 + lr, d0 = kk * 32 + lg * 8;
            af[m] = *reinterpret_cast<const short8*>(&A[r * 128 + (d0 ^ ((r & 7) << 3))]);
        }
        #pragma unroll
        for (int n = 0; n < 2; ++n) {
            int c = w * 32 + n * 16 + lr;
            short8 bf = *reinterpret_cast<const short8*>(WO + (size_t)c * 128 + kk * 32 + lg * 8);
            #pragma unroll
            for (int m = 0; m < 4; ++m)
                acc[m][n] = MFMA16(af[m], bf, acc[m][n]);
        }
    }
    #pragma unroll
    for (int n = 0; n < 2; ++n) {
        int c = w * 32 + n * 16 + lr;
        #pragma unroll
        for (int m = 0; m < 4; ++m) {
            #pragma unroll
            for (int rr = 0; rr < 4; ++rr) {
                int row = r0 + m * 16 + lg * 4 + rr;
                out[(size_t)row * 128 + c] = acc[m][n][rr];
            }
        }
    }
}

extern "C" void kernel_launch(void* const* d_in, const int* in_sizes, int n_in,
                              void* d_out, int out_size, void* d_ws, size_t ws_size,
                              hipStream_t stream)
{
    (void)in_sizes; (void)n_in; (void)out_size; (void)ws_size;
    const float* z     = (const float*)d_in[0];
    const float* nw    = (const float*)d_in[2];
    const float* nb    = (const float*)d_in[3];
    const float* wqkv  = (const float*)d_in[4];
    const float* wbias = (const float*)d_in[5];
    const float* wgate = (const float*)d_in[6];
    const float* wout  = (const float*)d_in[7];
    float* out = (float*)d_out;

    // ws layout
    float* bias = (float*)d_ws;                                   // 262144 f32 (1 MB)
    unsigned short* Qb = (unsigned short*)((char*)d_ws + (1 << 20)); // 4*65536*32
    unsigned short* Kb = Qb + 8388608ull;
    unsigned short* Vb = Kb + 8388608ull;
    unsigned short* Gb = Vb + 8388608ull;                          // 65536*128
    unsigned short* AOb = Gb + 8388608ull;                         // 65536*128
    unsigned short* WB = AOb + 8388608ull;                         // 512*128
    unsigned short* WO = WB + 65536ull;                            // 128*128

    prep_kernel<<<dim3(320), dim3(256), 0, stream>>>(wqkv, wgate, wout, WB, WO);
    ln_proj_kernel<<<dim3(1024), dim3(256), 0, stream>>>(z, nw, nb, wbias, WB,
                                                         Qb, Kb, Vb, Gb, bias);
    attn_kernel<<<dim3(1024), dim3(256), 0, stream>>>(Qb, Kb, Vb, bias, AOb);
    gateout_kernel<<<dim3(1024), dim3(256), 0, stream>>>(Gb, AOb, WO, out);
}

// Round 6
// 217.689 us; speedup vs baseline: 1.0398x; 1.0398x over previous
//
#include <hip/hip_runtime.h>
#include <hip/hip_bf16.h>
#include <math.h>

// TriangleAttention B=1,N=256,D=128,H=4,DH=32. Round 6: ln_proj v4 —
// col-split grid (2048 blocks) + branch-free LDS-staged coalesced epilogue.
// attn/gateout unchanged from the passing round-4/5 build.
//  K1 ln_proj: register LN -> bf16 A (XOR-swizzled LDS) -> per-wave 64x64 MFMA GEMM
//              -> stage C in LDS (bf16, [col][row]) -> coalesced dwordx4 stores.
//              half 0 blocks: Q,K (+pair-bias); half 1 blocks: V,gate(sigmoid).

#define NDIM 256
#define DDIM 128
#define NROWS 65536
#define ATT_SCALE 0.17677669529663687f
#define LN_EPS 1e-5f

typedef __attribute__((ext_vector_type(8))) short short8;
typedef __attribute__((ext_vector_type(4))) short short4v;
typedef __attribute__((ext_vector_type(4))) float f32x4;

#define MFMA16(a, b, c) __builtin_amdgcn_mfma_f32_16x16x32_bf16((a), (b), (c), 0, 0, 0)

__device__ inline unsigned short f2b(float x) {
    __hip_bfloat16 h = __float2bfloat16(x);
    return *reinterpret_cast<unsigned short*>(&h);
}
__device__ inline float b2f(unsigned short u) {
    return __uint_as_float(((unsigned int)u) << 16);
}

// ---------------- K0: weight prep ----------------
__global__ __launch_bounds__(256) void prep_kernel(
    const float* __restrict__ wqkv, const float* __restrict__ wgate,
    const float* __restrict__ wout,
    unsigned short* __restrict__ WB, unsigned short* __restrict__ WO)
{
    int idx = blockIdx.x * 256 + threadIdx.x;
    if (idx < 49152)      WB[idx] = f2b(wqkv[idx]);
    else if (idx < 65536) WB[idx] = f2b(wgate[idx - 49152]);
    else if (idx < 81920) WO[idx - 65536] = f2b(wout[idx - 65536]);
}

// ---------------- K1: LN + projections (v4) ----------------
// grid 2048: tile = bid>>1 (64 rows), half = bid&1 (0: cols 0-255 = Q,K; 1: cols 256-511 = V,gate)
__global__ __launch_bounds__(256) void ln_proj_kernel(
    const float* __restrict__ z, const float* __restrict__ nw, const float* __restrict__ nb,
    const float* __restrict__ wbias, const unsigned short* __restrict__ WB,
    unsigned short* __restrict__ Qb, unsigned short* __restrict__ Kb,
    unsigned short* __restrict__ Vb, unsigned short* __restrict__ Gb,
    float* __restrict__ bias)
{
    __shared__ __align__(16) unsigned short A[64 * 128];      // 16 KB
    __shared__ __align__(16) unsigned short S[4][64 * 68];    // 4 x 8.5 KB stage, [col][row] pad 68
    const int tid = threadIdx.x;
    const int half = blockIdx.x & 1;
    const int r0 = (blockIdx.x >> 1) * 64;
    const int r = tid >> 2;
    const int part = tid & 3;
    const int d0 = part * 32;

    // --- register LN (v3, verified) ---
    float4 zv[8];
    const float* zrow = z + (size_t)(r0 + r) * DDIM + d0;
    #pragma unroll
    for (int t = 0; t < 8; ++t) zv[t] = *reinterpret_cast<const float4*>(zrow + t * 4);

    float s1 = 0.f, s2 = 0.f;
    #pragma unroll
    for (int t = 0; t < 8; ++t) {
        s1 += zv[t].x + zv[t].y + zv[t].z + zv[t].w;
        s2 += zv[t].x * zv[t].x + zv[t].y * zv[t].y + zv[t].z * zv[t].z + zv[t].w * zv[t].w;
    }
    s1 += __shfl_xor(s1, 1); s2 += __shfl_xor(s2, 1);
    s1 += __shfl_xor(s1, 2); s2 += __shfl_xor(s2, 2);
    const float mu = s1 * (1.0f / 128.0f);
    const float rs = rsqrtf(s2 * (1.0f / 128.0f) - mu * mu + LN_EPS);

    float zn[32];
    #pragma unroll
    for (int t = 0; t < 8; ++t) {
        float4 wv = *reinterpret_cast<const float4*>(nw + d0 + t * 4);
        float4 bv = *reinterpret_cast<const float4*>(nb + d0 + t * 4);
        zn[t * 4 + 0] = (zv[t].x - mu) * rs * wv.x + bv.x;
        zn[t * 4 + 1] = (zv[t].y - mu) * rs * wv.y + bv.y;
        zn[t * 4 + 2] = (zv[t].z - mu) * rs * wv.z + bv.z;
        zn[t * 4 + 3] = (zv[t].w - mu) * rs * wv.w + bv.w;
    }

    // pair bias (only half-0 blocks)
    if (half == 0) {
        float p[4];
        #pragma unroll
        for (int h = 0; h < 4; ++h) {
            const float* wb = wbias + h * DDIM + d0;
            float acc = 0.f;
            #pragma unroll
            for (int t = 0; t < 8; ++t) {
                float4 wv = *reinterpret_cast<const float4*>(wb + t * 4);
                acc += zn[t * 4 + 0] * wv.x + zn[t * 4 + 1] * wv.y
                     + zn[t * 4 + 2] * wv.z + zn[t * 4 + 3] * wv.w;
            }
            p[h] = acc;
        }
        #pragma unroll
        for (int h = 0; h < 4; ++h) {
            p[h] += __shfl_xor(p[h], 1);
            p[h] += __shfl_xor(p[h], 2);
        }
        float sel = (part == 0) ? p[0] : (part == 1) ? p[1] : (part == 2) ? p[2] : p[3];
        bias[(size_t)part * NROWS + r0 + r] = sel;
    }

    // pack zn -> swizzled A
    #pragma unroll
    for (int e = 0; e < 4; ++e) {
        short8 t;
        #pragma unroll
        for (int q = 0; q < 8; ++q) t[q] = (short)f2b(zn[e * 8 + q]);
        int dd = d0 + e * 8;
        *reinterpret_cast<short8*>(&A[r * 128 + (dd ^ ((r & 7) << 3))]) = t;
    }
    __syncthreads();

    // --- MFMA GEMM: this wave owns 64 rows x 64 cols ---
    const int w = tid >> 6, lane = tid & 63, lr = lane & 15, lg = lane >> 4;
    const int cb = half * 256 + w * 64;   // global col base of this wave
    f32x4 acc[4][4] = {};
    #pragma unroll
    for (int kk = 0; kk < 4; ++kk) {
        short8 af[4];
        #pragma unroll
        for (int m = 0; m < 4; ++m) {
            int rr_ = m * 16 + lr, dd = kk * 32 + lg * 8;
            af[m] = *reinterpret_cast<const short8*>(&A[rr_ * 128 + (dd ^ ((rr_ & 7) << 3))]);
        }
        #pragma unroll
        for (int n = 0; n < 4; ++n) {
            int c = cb + n * 16 + lr;
            short8 bf = *reinterpret_cast<const short8*>(WB + (size_t)c * 128 + kk * 32 + lg * 8);
            #pragma unroll
            for (int m = 0; m < 4; ++m)
                acc[m][n] = MFMA16(af[m], bf, acc[m][n]);
        }
    }

    // --- epilogue: wave role (uniform) ---
    const bool is_gate = (half == 1) && (w >= 2);
    if (is_gate) {
        #pragma unroll
        for (int m = 0; m < 4; ++m)
            #pragma unroll
            for (int n = 0; n < 4; ++n)
                #pragma unroll
                for (int rr = 0; rr < 4; ++rr)
                    acc[m][n][rr] = 1.0f / (1.0f + __expf(-acc[m][n][rr]));
    }

    // stage to S[w]: [col 64][row 68-pad] bf16; lane packs 4 consecutive rows per b64
    #pragma unroll
    for (int n = 0; n < 4; ++n) {
        int col = n * 16 + lr;
        #pragma unroll
        for (int m = 0; m < 4; ++m) {
            int row = m * 16 + lg * 4;
            short4v pk;
            pk[0] = (short)f2b(acc[m][n][0]);
            pk[1] = (short)f2b(acc[m][n][1]);
            pk[2] = (short)f2b(acc[m][n][2]);
            pk[3] = (short)f2b(acc[m][n][3]);
            *reinterpret_cast<short4v*>(&S[w][col * 68 + row]) = pk;
        }
    }
    // same-wave LDS write->read: compiler inserts lgkmcnt; no __syncthreads needed.

    // transpose-read + coalesced store: lane = row j
    const int j = lane;
    #pragma unroll
    for (int seg = 0; seg < 2; ++seg) {
        unsigned int u[16];
        #pragma unroll
        for (int p2 = 0; p2 < 16; ++p2) {
            unsigned short lo = S[w][(seg * 32 + p2 * 2 + 0) * 68 + j];
            unsigned short hi = S[w][(seg * 32 + p2 * 2 + 1) * 68 + j];
            u[p2] = (unsigned int)lo | ((unsigned int)hi << 16);
        }
        unsigned short* dst;
        if (!is_gate) {
            const int h = (w & 1) * 2 + seg;
            unsigned short* buf = (half == 0) ? ((w < 2) ? Qb : Kb)
                                              : Vb;
            dst = buf + ((size_t)h * NROWS + r0 + j) * 32;
        } else {
            dst = Gb + (size_t)(r0 + j) * 128 + (w & 1) * 64 + seg * 32;
        }
        #pragma unroll
        for (int q = 0; q < 4; ++q) {
            uint4 o = {u[q * 4 + 0], u[q * 4 + 1], u[q * 4 + 2], u[q * 4 + 3]};
            *reinterpret_cast<uint4*>(dst + q * 8) = o;
        }
    }
}

// ---------------- K2: attention (unchanged) ----------------
__global__ __launch_bounds__(256) void attn_kernel(
    const unsigned short* __restrict__ Qb, const unsigned short* __restrict__ Kb,
    const unsigned short* __restrict__ Vb, const float* __restrict__ bias,
    unsigned short* __restrict__ ao)
{
    __shared__ __align__(16) unsigned short k_lds[256 * 40];   // pad 40: bank-safe
    __shared__ __align__(16) unsigned short vt_lds[32 * 264];  // V^T, pad 264
    __shared__ __align__(16) unsigned short p_lds[4][64 * 40];
    const int i = blockIdx.x >> 2, h = blockIdx.x & 3;
    const int tid = threadIdx.x;

    {   // stage K (row-major) and V^T
        int j = tid;
        const unsigned short* ks = Kb + ((size_t)h * NROWS + i * 256 + j) * 32;
        const unsigned short* vs = Vb + ((size_t)h * NROWS + i * 256 + j) * 32;
        #pragma unroll
        for (int c = 0; c < 4; ++c)
            *reinterpret_cast<short8*>(&k_lds[j * 40 + c * 8]) =
                *reinterpret_cast<const short8*>(ks + c * 8);
        unsigned short vv[32];
        #pragma unroll
        for (int c = 0; c < 4; ++c)
            *reinterpret_cast<short8*>(&vv[c * 8]) =
                *reinterpret_cast<const short8*>(vs + c * 8);
        #pragma unroll
        for (int d = 0; d < 32; ++d) vt_lds[d * 264 + j] = vv[d];
    }

    const int w = tid >> 6, lane = tid & 63, lr = lane & 15, lg = lane >> 4;
    short8 qf[4];
    #pragma unroll
    for (int m = 0; m < 4; ++m) {
        int jq = w * 64 + m * 16 + lr;
        qf[m] = *reinterpret_cast<const short8*>(
            Qb + ((size_t)h * NROWS + i * 256 + jq) * 32 + lg * 8);
    }
    f32x4 o[4][2] = {};
    float lsum[4][4] = {};
    const float* bb = bias + (size_t)h * NROWS;
    __syncthreads();

    for (int t = 0; t < 8; ++t) {
        const int k0 = t * 32;
        short8 kf[2];
        #pragma unroll
        for (int n = 0; n < 2; ++n)
            kf[n] = *reinterpret_cast<const short8*>(&k_lds[(k0 + n * 16 + lr) * 40 + lg * 8]);
        f32x4 s[4][2];
        #pragma unroll
        for (int m = 0; m < 4; ++m) {
            #pragma unroll
            for (int n = 0; n < 2; ++n) {
                f32x4 zz = {0.f, 0.f, 0.f, 0.f};
                s[m][n] = MFMA16(qf[m], kf[n], zz);
            }
        }
        // bias + exp (no max-subtraction: |S| bounded), write P bf16
        #pragma unroll
        for (int m = 0; m < 4; ++m) {
            #pragma unroll
            for (int rr = 0; rr < 4; ++rr) {
                int jq = w * 64 + m * 16 + lg * 4 + rr;
                #pragma unroll
                for (int n = 0; n < 2; ++n) {
                    int kc = k0 + n * 16 + lr;
                    float sv = s[m][n][rr] * ATT_SCALE + bb[(size_t)jq * 256 + kc];
                    float p = __expf(sv);
                    lsum[m][rr] += p;
                    p_lds[w][(m * 16 + lg * 4 + rr) * 40 + n * 16 + lr] = f2b(p);
                }
            }
        }
        // PV
        short8 vf[2], pf[4];
        #pragma unroll
        for (int n = 0; n < 2; ++n)
            vf[n] = *reinterpret_cast<const short8*>(&vt_lds[(n * 16 + lr) * 264 + k0 + lg * 8]);
        #pragma unroll
        for (int m = 0; m < 4; ++m)
            pf[m] = *reinterpret_cast<const short8*>(&p_lds[w][(m * 16 + lr) * 40 + lg * 8]);
        #pragma unroll
        for (int m = 0; m < 4; ++m) {
            #pragma unroll
            for (int n = 0; n < 2; ++n)
                o[m][n] = MFMA16(pf[m], vf[n], o[m][n]);
        }
    }

    #pragma unroll
    for (int m = 0; m < 4; ++m) {
        #pragma unroll
        for (int rr = 0; rr < 4; ++rr) {
            float l = lsum[m][rr];
            l += __shfl_xor(l, 1); l += __shfl_xor(l, 2);
            l += __shfl_xor(l, 4); l += __shfl_xor(l, 8);
            float inv = 1.0f / l;
            int jq = w * 64 + m * 16 + lg * 4 + rr;
            #pragma unroll
            for (int n = 0; n < 2; ++n) {
                float v = o[m][n][rr] * inv;
                ao[(size_t)(i * 256 + jq) * 128 + h * 32 + n * 16 + lr] = f2b(v);
            }
        }
    }
}

// ---------------- K3: gate * ao @ w_out (unchanged) ----------------
__global__ __launch_bounds__(256) void gateout_kernel(
    const unsigned short* __restrict__ Gb, const unsigned short* __restrict__ ao,
    const unsigned short* __restrict__ WO, float* __restrict__ out)
{
    __shared__ __align__(16) unsigned short A[64 * 128];
    const int tid = threadIdx.x;
    const int r0 = blockIdx.x * 64;

    for (int c = tid; c < 64 * 16; c += 256) {
        int r = c >> 4, d0 = (c & 15) * 8;
        size_t off = (size_t)(r0 + r) * 128 + d0;
        short8 gv = *reinterpret_cast<const short8*>(Gb + off);
        short8 av = *reinterpret_cast<const short8*>(ao + off);
        short8 t;
        #pragma unroll
        for (int e = 0; e < 8; ++e)
            t[e] = (short)f2b(b2f((unsigned short)gv[e]) * b2f((unsigned short)av[e]));
        *reinterpret_cast<short8*>(&A[r * 128 + (d0 ^ ((r & 7) << 3))]) = t;
    }
    __syncthreads();

    const int w = tid >> 6, lane = tid & 63, lr = lane & 15, lg = lane >> 4;
    f32x4 acc[4][2] = {};
    #pragma unroll
    for (int kk = 0; kk < 4; ++kk) {
        short8 af[4];
        #pragma unroll
        for (int m = 0; m < 4; ++m) {
            int r = m * 16 + lr, d0 = kk * 32 + lg * 8;
            af[m] = *reinterpret_cast<const short8*>(&A[r * 128 + (d0 ^ ((r & 7) << 3))]);
        }
        #pragma unroll
        for (int n = 0; n < 2; ++n) {
            int c = w * 32 + n * 16 + lr;
            short8 bf = *reinterpret_cast<const short8*>(WO + (size_t)c * 128 + kk * 32 + lg * 8);
            #pragma unroll
            for (int m = 0; m < 4; ++m)
                acc[m][n] = MFMA16(af[m], bf, acc[m][n]);
        }
    }
    #pragma unroll
    for (int n = 0; n < 2; ++n) {
        int c = w * 32 + n * 16 + lr;
        #pragma unroll
        for (int m = 0; m < 4; ++m) {
            #pragma unroll
            for (int rr = 0; rr < 4; ++rr) {
                int row = r0 + m * 16 + lg * 4 + rr;
                out[(size_t)row * 128 + c] = acc[m][n][rr];
            }
        }
    }
}

extern "C" void kernel_launch(void* const* d_in, const int* in_sizes, int n_in,
                              void* d_out, int out_size, void* d_ws, size_t ws_size,
                              hipStream_t stream)
{
    (void)in_sizes; (void)n_in; (void)out_size; (void)ws_size;
    const float* z     = (const float*)d_in[0];
    const float* nw    = (const float*)d_in[2];
    const float* nb    = (const float*)d_in[3];
    const float* wqkv  = (const float*)d_in[4];
    const float* wbias = (const float*)d_in[5];
    const float* wgate = (const float*)d_in[6];
    const float* wout  = (const float*)d_in[7];
    float* out = (float*)d_out;

    // ws layout
    float* bias = (float*)d_ws;                                   // 262144 f32 (1 MB)
    unsigned short* Qb = (unsigned short*)((char*)d_ws + (1 << 20)); // 4*65536*32
    unsigned short* Kb = Qb + 8388608ull;
    unsigned short* Vb = Kb + 8388608ull;
    unsigned short* Gb = Vb + 8388608ull;                          // 65536*128
    unsigned short* AOb = Gb + 8388608ull;                         // 65536*128
    unsigned short* WB = AOb + 8388608ull;                         // 512*128
    unsigned short* WO = WB + 65536ull;                            // 128*128

    prep_kernel<<<dim3(320), dim3(256), 0, stream>>>(wqkv, wgate, wout, WB, WO);
    ln_proj_kernel<<<dim3(2048), dim3(256), 0, stream>>>(z, nw, nb, wbias, WB,
                                                         Qb, Kb, Vb, Gb, bias);
    attn_kernel<<<dim3(1024), dim3(256), 0, stream>>>(Qb, Kb, Vb, bias, AOb);
    gateout_kernel<<<dim3(1024), dim3(256), 0, stream>>>(Gb, AOb, WO, out);
}